// Round 2
// baseline (986.798 us; speedup 1.0000x reference)
//
#include <hip/hip_runtime.h>
#include <stdint.h>

// SparseMoE: B=4,S=2048,D=1024,E=8,H=2048, top-k=2.
// Outputs (concat, float32): final_output[8192*1024], top_k_indices[8192*2] (as floats), aux_loss[1].

#define NTOK   8192
#define DIM    1024
#define NEXP   8
#define HID    2048
#define OUT_MAIN (NTOK * DIM)          // 8388608
#define IDX_OFF  OUT_MAIN
#define AUX_OFF  (OUT_MAIN + NTOK * 2) // 8404992

typedef __attribute__((ext_vector_type(8))) short short8;
typedef __attribute__((ext_vector_type(4))) float floatx4;

__device__ __forceinline__ unsigned short f2bf(float f) {
  unsigned int b = __float_as_uint(f);
  b += 0x7FFFu + ((b >> 16) & 1u);      // RNE; inputs finite
  return (unsigned short)(b >> 16);
}

// ---------------- gating: logits (fp64 acc), top-2, masked softmax, scatter, xb=bf16(x) ---
__global__ __launch_bounds__(256) void k_gating(
    const float* __restrict__ x, const float* __restrict__ gate_w,
    const float* __restrict__ gate_b, const float* __restrict__ noise,
    float* __restrict__ out, int* __restrict__ counts,
    int* __restrict__ lists_tok, float* __restrict__ lists_p,
    float* __restrict__ probs_all, unsigned short* __restrict__ xb)
{
  const int lane = threadIdx.x & 63;
  const int wv   = threadIdx.x >> 6;
  const int t    = blockIdx.x * 4 + wv;           // one token per wave
  const float* xr = x + (size_t)t * DIM;
  double acc[NEXP] = {0,0,0,0,0,0,0,0};
  #pragma unroll
  for (int jj = 0; jj < 4; ++jj) {
    const int d0 = lane * 4 + jj * 256;
    const float4 xv = *(const float4*)(xr + d0);
    const float xs[4] = {xv.x, xv.y, xv.z, xv.w};
    unsigned short xbq[4];
    #pragma unroll
    for (int c = 0; c < 4; ++c) {
      const float4 g0 = *(const float4*)(gate_w + (size_t)(d0 + c) * NEXP);
      const float4 g1 = *(const float4*)(gate_w + (size_t)(d0 + c) * NEXP + 4);
      const double xd = (double)xs[c];
      acc[0] += xd * (double)g0.x; acc[1] += xd * (double)g0.y;
      acc[2] += xd * (double)g0.z; acc[3] += xd * (double)g0.w;
      acc[4] += xd * (double)g1.x; acc[5] += xd * (double)g1.y;
      acc[6] += xd * (double)g1.z; acc[7] += xd * (double)g1.w;
      xbq[c] = f2bf(xs[c]);
    }
    ushort4 q; q.x = xbq[0]; q.y = xbq[1]; q.z = xbq[2]; q.w = xbq[3];
    *(ushort4*)(xb + (size_t)t * DIM + d0) = q;
  }
  #pragma unroll
  for (int e = 0; e < NEXP; ++e) {
    #pragma unroll
    for (int off = 32; off; off >>= 1) acc[e] += __shfl_xor(acc[e], off);
  }
  if (lane == 0) {
    double l[NEXP];
    #pragma unroll
    for (int e = 0; e < NEXP; ++e)
      l[e] = acc[e] + (double)gate_b[e] + 0.01 * (double)noise[(size_t)t * NEXP + e];
    // top-2 with jax.lax.top_k tie semantics (stable desc: earliest index wins)
    int i1 = 0; double v1 = l[0];
    #pragma unroll
    for (int e = 1; e < NEXP; ++e) if (l[e] > v1) { v1 = l[e]; i1 = e; }
    int i2 = (i1 == 0) ? 1 : 0; double v2 = l[i2];
    #pragma unroll
    for (int e = 0; e < NEXP; ++e) if (e != i1 && l[e] > v2) { v2 = l[e]; i2 = e; }
    // masked softmax over all 8 (mask = logit >= v2), max is v1
    float pr[NEXP]; float Z = 0.f;
    #pragma unroll
    for (int e = 0; e < NEXP; ++e) {
      const float a = (l[e] >= v2) ? (float)(l[e] - v1) : -1.0e9f;
      pr[e] = __expf(a); Z += pr[e];
    }
    const float rz = 1.0f / Z;
    #pragma unroll
    for (int e = 0; e < NEXP; ++e) {
      pr[e] *= rz;
      probs_all[(size_t)t * NEXP + e] = pr[e];
    }
    out[(size_t)IDX_OFF + t * 2]     = (float)i1;
    out[(size_t)IDX_OFF + t * 2 + 1] = (float)i2;
    int p1 = atomicAdd(&counts[i1], 1);
    lists_tok[i1 * NTOK + p1] = t; lists_p[i1 * NTOK + p1] = pr[i1];
    int p2 = atomicAdd(&counts[i2], 1);
    lists_tok[i2 * NTOK + p2] = t; lists_p[i2 * NTOK + p2] = pr[i2];
  }
}

__global__ void k_offs(const int* __restrict__ counts, int* __restrict__ offs) {
  if (threadIdx.x == 0) {
    int a = 0;
    #pragma unroll
    for (int e = 0; e < NEXP; ++e) { offs[e] = a; a += counts[e]; }
    offs[NEXP] = a;
  }
}

// ---------------- aux loss ----------------
__global__ __launch_bounds__(256) void k_aux(const float* __restrict__ probs_all,
                                             float* __restrict__ out) {
  float p[NEXP] = {0,0,0,0,0,0,0,0};
  for (int t = threadIdx.x; t < NTOK; t += 256) {
    const float4 a = *(const float4*)(probs_all + (size_t)t * NEXP);
    const float4 b = *(const float4*)(probs_all + (size_t)t * NEXP + 4);
    p[0] += a.x; p[1] += a.y; p[2] += a.z; p[3] += a.w;
    p[4] += b.x; p[5] += b.y; p[6] += b.z; p[7] += b.w;
  }
  #pragma unroll
  for (int e = 0; e < NEXP; ++e) {
    #pragma unroll
    for (int off = 32; off; off >>= 1) p[e] += __shfl_xor(p[e], off);
  }
  __shared__ float red[4][NEXP];
  const int lane = threadIdx.x & 63, wv = threadIdx.x >> 6;
  if (lane == 0) {
    #pragma unroll
    for (int e = 0; e < NEXP; ++e) red[wv][e] = p[e];
  }
  __syncthreads();
  if (threadIdx.x == 0) {
    float usage[NEXP], s = 0.f;
    #pragma unroll
    for (int e = 0; e < NEXP; ++e) {
      usage[e] = red[0][e] + red[1][e] + red[2][e] + red[3][e];
      s += usage[e];
    }
    float imp[NEXP], mean = 0.f, var = 0.f;
    #pragma unroll
    for (int e = 0; e < NEXP; ++e) { imp[e] = usage[e] / s; mean += imp[e]; }
    mean *= 0.125f;
    #pragma unroll
    for (int e = 0; e < NEXP; ++e) { const float d = imp[e] - mean; var += d * d; }
    var *= 0.125f;
    out[AUX_OFF] = sqrtf(var) / (mean + 1e-10f);
  }
}

// ---------------- weight transpose+convert: in[e][r][c] fp32 -> out[e][c-c0][r-r0] bf16 ---
// Block = 64x64 tile. tr=blockIdx.x*64 (local row in slice), tc=blockIdx.y*64 (local col).
__global__ __launch_bounds__(256) void k_tr(
    const float* __restrict__ in, unsigned short* __restrict__ out,
    int in_ld, size_t in_estride, int r0, int c0,
    int out_ld, size_t out_estride)
{
  const int e  = blockIdx.z;
  const int tr = blockIdx.x << 6;
  const int tc = blockIdx.y << 6;
  const int tid = threadIdx.x;
  __shared__ float t[64][65];
  const float* src = in + (size_t)e * in_estride + (size_t)(r0 + tr) * in_ld + (c0 + tc);
  #pragma unroll
  for (int p = 0; p < 4; ++p) {
    const int r  = (p << 4) + (tid >> 4);
    const int c4 = (tid & 15) << 2;
    const float4 v = *(const float4*)(src + (size_t)r * in_ld + c4);
    t[r][c4] = v.x; t[r][c4 + 1] = v.y; t[r][c4 + 2] = v.z; t[r][c4 + 3] = v.w;
  }
  __syncthreads();
  unsigned short* dst = out + (size_t)e * out_estride + (size_t)tc * out_ld + tr;
  #pragma unroll
  for (int p = 0; p < 4; ++p) {
    const int c  = (p << 4) + (tid >> 4);
    const int r4 = (tid & 15) << 2;
    ushort4 q;
    q.x = f2bf(t[r4][c]);     q.y = f2bf(t[r4 + 1][c]);
    q.z = f2bf(t[r4 + 2][c]); q.w = f2bf(t[r4 + 3][c]);
    *(ushort4*)(dst + (size_t)c * out_ld + r4) = q;
  }
}

// ---------------- grouped MFMA GEMM (m97 structure: both operands global_load_lds) ----
// MODE 0: h[slot, nb+n] = silu( xb[tok] @ w1t[e][nb+n][:] + b1 )   (K = 1024, N = Hs)
// MODE 1: out[tok, nb+n] += p * ( h[slot] @ w2t[e][nb+n][:] + b2 ) (K = Hs, N = 1024)
// 128x128 tile, 4 waves (2x2), 16x16x32 bf16 MFMA, BK=64, LDS [row][64] linear.
template <int MODE>
__global__ __launch_bounds__(256) void k_gemm(
    const unsigned short* __restrict__ Abase,
    const unsigned short* __restrict__ Bt,
    const float* __restrict__ bias,
    const int* __restrict__ counts, const int* __restrict__ offs,
    const int* __restrict__ lists_tok, const float* __restrict__ lists_p,
    unsigned short* __restrict__ hout, float* __restrict__ out,
    const int hb, const int Hs)
{
  const int e   = blockIdx.z;
  const int n_e = counts[e];
  const int m0  = blockIdx.x << 7;
  if (m0 >= n_e) return;
  const int nb   = blockIdx.y << 7;
  const int tid  = threadIdx.x;
  const int lane = tid & 63;
  const int wv   = tid >> 6;
  const int wm   = (wv & 1) << 6;
  const int wn   = (wv >> 1) << 6;

  __shared__ __align__(16) unsigned short as[128 * 64];  // A tile [row][k], 16 KB
  __shared__ __align__(16) unsigned short bs[128 * 64];  // B tile [n][k], 16 KB

  const int    K        = (MODE == 0) ? DIM : Hs;
  const size_t Bestride = (size_t)DIM * Hs;
  const unsigned short* Bexp = Bt + (size_t)e * Bestride + (size_t)nb * K;

  // hoist per-row global pointers (independent of kk)
  const unsigned short* gpa[4];
  const unsigned short* gpb[4];
  unsigned short* lpa[4];
  unsigned short* lpb[4];
  #pragma unroll
  for (int ii = 0; ii < 4; ++ii) {
    const int rbase = (wv << 5) + (ii << 3);
    const int r  = rbase + (lane >> 3);
    const int rc = (m0 + r < n_e) ? (m0 + r) : (n_e - 1);
    size_t arow;
    if (MODE == 0) arow = (size_t)lists_tok[e * NTOK + rc] * DIM;
    else           arow = (size_t)(offs[e] + rc) * Hs;
    gpa[ii] = Abase + arow + ((lane & 7) << 3);
    gpb[ii] = Bexp + (size_t)r * K + ((lane & 7) << 3);
    lpa[ii] = as + (rbase << 6);
    lpb[ii] = bs + (rbase << 6);
  }

  floatx4 acc[4][4];
  #pragma unroll
  for (int i = 0; i < 4; ++i)
    #pragma unroll
    for (int j = 0; j < 4; ++j) acc[i][j] = (floatx4){0.f, 0.f, 0.f, 0.f};

  for (int kk = 0; kk < K; kk += 64) {
    __syncthreads();
    #pragma unroll
    for (int ii = 0; ii < 4; ++ii) {
      __builtin_amdgcn_global_load_lds(
          (const __attribute__((address_space(1))) void*)(gpa[ii] + kk),
          (__attribute__((address_space(3))) void*)(void*)lpa[ii], 16, 0, 0);
      __builtin_amdgcn_global_load_lds(
          (const __attribute__((address_space(1))) void*)(gpb[ii] + kk),
          (__attribute__((address_space(3))) void*)(void*)lpb[ii], 16, 0, 0);
    }
    __syncthreads();
    #pragma unroll
    for (int ks = 0; ks < 2; ++ks) {
      const int k0 = (ks << 5) + ((lane >> 4) << 3);
      short8 af[4];
      #pragma unroll
      for (int i = 0; i < 4; ++i)
        af[i] = *(const short8*)((const short*)as + ((wm + (i << 4) + (lane & 15)) << 6) + k0);
      short8 bfr[4];
      #pragma unroll
      for (int j = 0; j < 4; ++j)
        bfr[j] = *(const short8*)((const short*)bs + ((wn + (j << 4) + (lane & 15)) << 6) + k0);
      #pragma unroll
      for (int i = 0; i < 4; ++i)
        #pragma unroll
        for (int j = 0; j < 4; ++j)
          acc[i][j] = __builtin_amdgcn_mfma_f32_16x16x32_bf16(af[i], bfr[j], acc[i][j], 0, 0, 0);
    }
  }

  // epilogue: C/D map col=lane&15, row=(lane>>4)*4+r (m89-verified)
  const int q4 = (lane >> 4) << 2;
  if (MODE == 0) {
    #pragma unroll
    for (int i = 0; i < 4; ++i) {
      #pragma unroll
      for (int j = 0; j < 4; ++j) {
        const int nloc = wn + (j << 4) + (lane & 15);
        const float bb = bias[e * HID + hb + nb + nloc];
        #pragma unroll
        for (int r = 0; r < 4; ++r) {
          const int m = m0 + wm + (i << 4) + q4 + r;
          if (m < n_e) {
            float v = acc[i][j][r] + bb;
            v = v / (1.0f + __expf(-v));                 // silu
            hout[(size_t)(offs[e] + m) * Hs + nb + nloc] = f2bf(v);
          }
        }
      }
    }
  } else {
    #pragma unroll
    for (int i = 0; i < 4; ++i) {
      #pragma unroll
      for (int r = 0; r < 4; ++r) {
        const int m = m0 + wm + (i << 4) + q4 + r;
        if (m < n_e) {
          const int   tok = lists_tok[e * NTOK + m];
          const float p   = lists_p[e * NTOK + m];
          #pragma unroll
          for (int j = 0; j < 4; ++j) {
            const int d = nb + wn + (j << 4) + (lane & 15);
            float v = acc[i][j][r];
            if (hb == 0) v += bias[e * DIM + d];         // add b2 once (first H-slice)
            atomicAdd(out + (size_t)tok * DIM + d, p * v);
          }
        }
      }
    }
  }
}

extern "C" void kernel_launch(void* const* d_in, const int* in_sizes, int n_in,
                              void* d_out, int out_size, void* d_ws, size_t ws_size,
                              hipStream_t stream)
{
  const float* x      = (const float*)d_in[0];
  const float* gate_w = (const float*)d_in[1];
  const float* gate_b = (const float*)d_in[2];
  const float* w1     = (const float*)d_in[3];
  const float* b1     = (const float*)d_in[4];
  const float* w2     = (const float*)d_in[5];
  const float* b2     = (const float*)d_in[6];
  const float* noise  = (const float*)d_in[7];
  float* out = (float*)d_out;

  char* ws = (char*)d_ws;
  // ws layout (bytes):
  const size_t CNT_OFF = 0;          // int counts[8]
  const size_t OFF_OFF = 64;         // int offs[9]
  const size_t LT_OFF  = 128;        // int  lists_tok[8][8192]   (256 KB)
  const size_t LP_OFF  = 262272;     // f32  lists_p  [8][8192]   (256 KB)
  const size_t PA_OFF  = 524416;     // f32  probs_all[8192][8]   (256 KB)
  const size_t XB_OFF  = 1048576;    // bf16 xb[8192][1024]       (16 MB)
  const size_t W_OFF   = 17825792;   // bf16 weight-slice buffer  (32 MB / nsl), reused for w1t then w2t

  // pick H-slicing: need = W_OFF + 32MB/nsl (wt) + 64MB/nsl (h)
  int nsl = 0;
  for (int cand = 1; cand <= 16; cand <<= 1) {
    const size_t need = W_OFF + (size_t)(33554432 + 67108864) / (size_t)cand;
    if (ws_size >= need) { nsl = cand; break; }
  }
  if (!nsl) return;
  const int Hs = HID / nsl;

  int* counts          = (int*)(ws + CNT_OFF);
  int* offs            = (int*)(ws + OFF_OFF);
  int* lists_tok       = (int*)(ws + LT_OFF);
  float* lists_p       = (float*)(ws + LP_OFF);
  float* probs_all     = (float*)(ws + PA_OFF);
  unsigned short* xb   = (unsigned short*)(ws + XB_OFF);
  unsigned short* wt   = (unsigned short*)(ws + W_OFF);
  unsigned short* hbuf = (unsigned short*)(ws + W_OFF + (size_t)33554432 / nsl);

  hipMemsetAsync(d_out, 0, (size_t)OUT_MAIN * sizeof(float), stream);
  hipMemsetAsync(ws + CNT_OFF, 0, 64, stream);

  k_gating<<<NTOK / 4, 256, 0, stream>>>(x, gate_w, gate_b, noise, out, counts,
                                         lists_tok, lists_p, probs_all, xb);
  k_offs<<<1, 64, 0, stream>>>(counts, offs);
  k_aux<<<1, 256, 0, stream>>>(probs_all, out);

  for (int s = 0; s < nsl; ++s) {
    const int hb = s * Hs;
    // w1t slice: in w1[e][d][h], rows d (full 1024), cols h in [hb,hb+Hs) -> wt[e][h'][d]
    dim3 gt1(DIM / 64, Hs / 64, NEXP);
    k_tr<<<gt1, 256, 0, stream>>>(w1, wt, HID, (size_t)DIM * HID, 0, hb,
                                  DIM, (size_t)Hs * DIM);
    dim3 g1(64, Hs / 128, NEXP);
    k_gemm<0><<<g1, 256, 0, stream>>>(xb, wt, b1, counts, offs, lists_tok, lists_p,
                                      hbuf, out, hb, Hs);
    // w2t slice: in w2[e][h][d], rows h in [hb,hb+Hs), cols d (full 1024) -> wt[e][d][h']
    dim3 gt2(Hs / 64, DIM / 64, NEXP);
    k_tr<<<gt2, 256, 0, stream>>>(w2, wt, DIM, (size_t)DIM * HID, hb, 0,
                                  Hs, (size_t)DIM * Hs);
    dim3 g2(64, DIM / 128, NEXP);
    k_gemm<1><<<g2, 256, 0, stream>>>(hbuf, wt, b2, counts, offs, lists_tok, lists_p,
                                      hbuf, out, hb, Hs);
  }
}

// Round 3
// 778.950 us; speedup vs baseline: 1.2668x; 1.2668x over previous
//
#include <hip/hip_runtime.h>
#include <stdint.h>

// SparseMoE: B=4,S=2048,D=1024,E=8,H=2048, top-k=2.
// Outputs (concat, float32): final_output[8192*1024], top_k_indices[8192*2] (as floats), aux_loss[1].

#define NTOK   8192
#define DIM    1024
#define NEXP   8
#define HID    2048
#define OUT_MAIN (NTOK * DIM)          // 8388608
#define IDX_OFF  OUT_MAIN
#define AUX_OFF  (OUT_MAIN + NTOK * 2) // 8404992
#define MAXBLK 144                     // >= 128 + 7 worst-case m-blocks over 8 experts

typedef __attribute__((ext_vector_type(8))) short short8;
typedef __attribute__((ext_vector_type(4))) float floatx4;

__device__ __forceinline__ unsigned short f2bf(float f) {
  unsigned int b = __float_as_uint(f);
  b += 0x7FFFu + ((b >> 16) & 1u);      // RNE; inputs finite
  return (unsigned short)(b >> 16);
}

// ---------------- gating: logits (fp64 acc), top-2, masked softmax, scatter, xb=bf16(x) ---
__global__ __launch_bounds__(256) void k_gating(
    const float* __restrict__ x, const float* __restrict__ gate_w,
    const float* __restrict__ gate_b, const float* __restrict__ noise,
    float* __restrict__ out, int* __restrict__ counts,
    int* __restrict__ lists_tok, float* __restrict__ lists_p,
    float* __restrict__ probs_all, unsigned short* __restrict__ xb)
{
  const int lane = threadIdx.x & 63;
  const int wv   = threadIdx.x >> 6;
  const int t    = blockIdx.x * 4 + wv;           // one token per wave
  const float* xr = x + (size_t)t * DIM;
  double acc[NEXP] = {0,0,0,0,0,0,0,0};
  #pragma unroll
  for (int jj = 0; jj < 4; ++jj) {
    const int d0 = lane * 4 + jj * 256;
    const float4 xv = *(const float4*)(xr + d0);
    const float xs[4] = {xv.x, xv.y, xv.z, xv.w};
    unsigned short xbq[4];
    #pragma unroll
    for (int c = 0; c < 4; ++c) {
      const float4 g0 = *(const float4*)(gate_w + (size_t)(d0 + c) * NEXP);
      const float4 g1 = *(const float4*)(gate_w + (size_t)(d0 + c) * NEXP + 4);
      const double xd = (double)xs[c];
      acc[0] += xd * (double)g0.x; acc[1] += xd * (double)g0.y;
      acc[2] += xd * (double)g0.z; acc[3] += xd * (double)g0.w;
      acc[4] += xd * (double)g1.x; acc[5] += xd * (double)g1.y;
      acc[6] += xd * (double)g1.z; acc[7] += xd * (double)g1.w;
      xbq[c] = f2bf(xs[c]);
    }
    ushort4 q; q.x = xbq[0]; q.y = xbq[1]; q.z = xbq[2]; q.w = xbq[3];
    *(ushort4*)(xb + (size_t)t * DIM + d0) = q;
  }
  #pragma unroll
  for (int e = 0; e < NEXP; ++e) {
    #pragma unroll
    for (int off = 32; off; off >>= 1) acc[e] += __shfl_xor(acc[e], off);
  }
  if (lane == 0) {
    double l[NEXP];
    #pragma unroll
    for (int e = 0; e < NEXP; ++e)
      l[e] = acc[e] + (double)gate_b[e] + 0.01 * (double)noise[(size_t)t * NEXP + e];
    // top-2 with jax.lax.top_k tie semantics (stable desc: earliest index wins)
    int i1 = 0; double v1 = l[0];
    #pragma unroll
    for (int e = 1; e < NEXP; ++e) if (l[e] > v1) { v1 = l[e]; i1 = e; }
    int i2 = (i1 == 0) ? 1 : 0; double v2 = l[i2];
    #pragma unroll
    for (int e = 0; e < NEXP; ++e) if (e != i1 && l[e] > v2) { v2 = l[e]; i2 = e; }
    // masked softmax over all 8 (mask = logit >= v2), max is v1
    float pr[NEXP]; float Z = 0.f;
    #pragma unroll
    for (int e = 0; e < NEXP; ++e) {
      const float a = (l[e] >= v2) ? (float)(l[e] - v1) : -1.0e9f;
      pr[e] = __expf(a); Z += pr[e];
    }
    const float rz = 1.0f / Z;
    #pragma unroll
    for (int e = 0; e < NEXP; ++e) {
      pr[e] *= rz;
      probs_all[(size_t)t * NEXP + e] = pr[e];
    }
    out[(size_t)IDX_OFF + t * 2]     = (float)i1;
    out[(size_t)IDX_OFF + t * 2 + 1] = (float)i2;
    int p1 = atomicAdd(&counts[i1], 1);
    lists_tok[i1 * NTOK + p1] = t; lists_p[i1 * NTOK + p1] = pr[i1];
    int p2 = atomicAdd(&counts[i2], 1);
    lists_tok[i2 * NTOK + p2] = t; lists_p[i2 * NTOK + p2] = pr[i2];
  }
}

// ---------------- offsets + block table (dud-block removal) ----------------
__global__ void k_offs(const int* __restrict__ counts, int* __restrict__ offs,
                       int* __restrict__ tbl_e, int* __restrict__ tbl_m,
                       int* __restrict__ nblk) {
  if (threadIdx.x == 0) {
    int a = 0;
    #pragma unroll
    for (int e = 0; e < NEXP; ++e) { offs[e] = a; a += counts[e]; }
    offs[NEXP] = a;
    int nb = 0;
    for (int e = 0; e < NEXP; ++e) {
      const int nbe = (counts[e] + 127) >> 7;
      for (int m = 0; m < nbe; ++m) { tbl_e[nb] = e; tbl_m[nb] = m << 7; ++nb; }
    }
    nblk[0] = nb;
    for (int b = nb; b < MAXBLK; ++b) { tbl_e[b] = 0; tbl_m[b] = 0; }
  }
}

// ---------------- aux loss ----------------
__global__ __launch_bounds__(256) void k_aux(const float* __restrict__ probs_all,
                                             float* __restrict__ out) {
  float p[NEXP] = {0,0,0,0,0,0,0,0};
  for (int t = threadIdx.x; t < NTOK; t += 256) {
    const float4 a = *(const float4*)(probs_all + (size_t)t * NEXP);
    const float4 b = *(const float4*)(probs_all + (size_t)t * NEXP + 4);
    p[0] += a.x; p[1] += a.y; p[2] += a.z; p[3] += a.w;
    p[4] += b.x; p[5] += b.y; p[6] += b.z; p[7] += b.w;
  }
  #pragma unroll
  for (int e = 0; e < NEXP; ++e) {
    #pragma unroll
    for (int off = 32; off; off >>= 1) p[e] += __shfl_xor(p[e], off);
  }
  __shared__ float red[4][NEXP];
  const int lane = threadIdx.x & 63, wv = threadIdx.x >> 6;
  if (lane == 0) {
    #pragma unroll
    for (int e = 0; e < NEXP; ++e) red[wv][e] = p[e];
  }
  __syncthreads();
  if (threadIdx.x == 0) {
    float usage[NEXP], s = 0.f;
    #pragma unroll
    for (int e = 0; e < NEXP; ++e) {
      usage[e] = red[0][e] + red[1][e] + red[2][e] + red[3][e];
      s += usage[e];
    }
    float imp[NEXP], mean = 0.f, var = 0.f;
    #pragma unroll
    for (int e = 0; e < NEXP; ++e) { imp[e] = usage[e] / s; mean += imp[e]; }
    mean *= 0.125f;
    #pragma unroll
    for (int e = 0; e < NEXP; ++e) { const float d = imp[e] - mean; var += d * d; }
    var *= 0.125f;
    out[AUX_OFF] = sqrtf(var) / (mean + 1e-10f);
  }
}

// ---------------- weight transpose+convert: in[e][r][c] fp32 -> out[e][c-c0][r-r0] bf16 ---
__global__ __launch_bounds__(256) void k_tr(
    const float* __restrict__ in, unsigned short* __restrict__ out,
    int in_ld, size_t in_estride, int r0, int c0,
    int out_ld, size_t out_estride)
{
  const int e  = blockIdx.z;
  const int tr = blockIdx.x << 6;
  const int tc = blockIdx.y << 6;
  const int tid = threadIdx.x;
  __shared__ float t[64][65];
  const float* src = in + (size_t)e * in_estride + (size_t)(r0 + tr) * in_ld + (c0 + tc);
  #pragma unroll
  for (int p = 0; p < 4; ++p) {
    const int r  = (p << 4) + (tid >> 4);
    const int c4 = (tid & 15) << 2;
    const float4 v = *(const float4*)(src + (size_t)r * in_ld + c4);
    t[r][c4] = v.x; t[r][c4 + 1] = v.y; t[r][c4 + 2] = v.z; t[r][c4 + 3] = v.w;
  }
  __syncthreads();
  unsigned short* dst = out + (size_t)e * out_estride + (size_t)tc * out_ld + tr;
  #pragma unroll
  for (int p = 0; p < 4; ++p) {
    const int c  = (p << 4) + (tid >> 4);
    const int r4 = (tid & 15) << 2;
    ushort4 q;
    q.x = f2bf(t[r4][c]);     q.y = f2bf(t[r4 + 1][c]);
    q.z = f2bf(t[r4 + 2][c]); q.w = f2bf(t[r4 + 3][c]);
    *(ushort4*)(dst + (size_t)c * out_ld + r4) = q;
  }
}

// ---------------- grouped MFMA GEMM, software-pipelined double-buffered LDS ----------
// MODE 0: h[slot, nb+n] = silu( xb[tok] @ w1t[e][nb+n][:] + b1 )   (K = 1024, N = Hs)
// MODE 1: out[tok, nb+n] += p * ( h[slot] @ w2t[e][nb+n][:] + b2 ) (K = Hs, N = 1024)
// 128x128 tile, 4 waves (2x2), 16x16x32 bf16 MFMA, BK=64.
// LDS [row][64] with 16B-chunk XOR swizzle: chunk c of row r stored at slot c^(r&7)
// (global source permuted per lane since global_load_lds dest is wave-base + lane*16).
template <int MODE>
__global__ __launch_bounds__(256) void k_gemm(
    const unsigned short* __restrict__ Abase,
    const unsigned short* __restrict__ Bt,
    const float* __restrict__ bias,
    const int* __restrict__ counts, const int* __restrict__ offs,
    const int* __restrict__ tbl_e, const int* __restrict__ tbl_m,
    const int* __restrict__ nblk,
    const int* __restrict__ lists_tok, const float* __restrict__ lists_p,
    unsigned short* __restrict__ hout, float* __restrict__ out,
    const int hb, const int Hs)
{
  if ((int)blockIdx.x >= nblk[0]) return;
  const int e   = tbl_e[blockIdx.x];
  const int m0  = tbl_m[blockIdx.x];
  const int n_e = counts[e];
  const int nb   = blockIdx.y << 7;
  const int tid  = threadIdx.x;
  const int lane = tid & 63;
  const int wv   = tid >> 6;
  const int wm   = (wv & 1) << 6;
  const int wn   = (wv >> 1) << 6;

  __shared__ __align__(16) unsigned short as[2][128 * 64];  // 2 x 16 KB
  __shared__ __align__(16) unsigned short bs[2][128 * 64];  // 2 x 16 KB

  const int    K    = (MODE == 0) ? DIM : Hs;
  const unsigned short* Bexp = Bt + (size_t)e * ((size_t)DIM * Hs) + (size_t)nb * K;

  // per-lane swizzled k-chunk within the 8-row staging group
  const int swk = (((lane & 7) ^ (lane >> 3)) << 3) & 63;   // element offset, 8 rows/call

  const unsigned short* gpa[4];
  const unsigned short* gpb[4];
  int lofs[4];
  #pragma unroll
  for (int ii = 0; ii < 4; ++ii) {
    const int rbase = (wv << 5) + (ii << 3);
    const int r  = rbase + (lane >> 3);
    const int rc = (m0 + r < n_e) ? (m0 + r) : (n_e - 1);
    size_t arow;
    if (MODE == 0) arow = (size_t)lists_tok[e * NTOK + rc] * DIM;
    else           arow = (size_t)(offs[e] + rc) * Hs;
    gpa[ii] = Abase + arow + swk;
    gpb[ii] = Bexp + (size_t)r * K + swk;
    lofs[ii] = rbase << 6;
  }

  floatx4 acc[4][4];
  #pragma unroll
  for (int i = 0; i < 4; ++i)
    #pragma unroll
    for (int j = 0; j < 4; ++j) acc[i][j] = (floatx4){0.f, 0.f, 0.f, 0.f};

  auto issue = [&](int buf, int kko) {
    #pragma unroll
    for (int ii = 0; ii < 4; ++ii) {
      __builtin_amdgcn_global_load_lds(
          (const __attribute__((address_space(1))) void*)(gpa[ii] + kko),
          (__attribute__((address_space(3))) void*)(void*)(&as[buf][lofs[ii]]), 16, 0, 0);
      __builtin_amdgcn_global_load_lds(
          (const __attribute__((address_space(1))) void*)(gpb[ii] + kko),
          (__attribute__((address_space(3))) void*)(void*)(&bs[buf][lofs[ii]]), 16, 0, 0);
    }
  };

  issue(0, 0);                                   // prologue: tile 0 in flight
  int p = 0;
  for (int kk = 0; kk < K; kk += 64) {
    __syncthreads();                             // drains tile-kk loads (vmcnt(0)+barrier)
    if (kk + 64 < K) issue(p ^ 1, kk + 64);      // next tile in flight during compute
    #pragma unroll
    for (int ks = 0; ks < 2; ++ks) {
      const int c = (ks << 2) + (lane >> 4);     // 16B-chunk index 0..7
      short8 af[4];
      #pragma unroll
      for (int i = 0; i < 4; ++i) {
        const int row = wm + (i << 4) + (lane & 15);
        af[i] = *(const short8*)(&as[p][(row << 6) + ((c ^ (row & 7)) << 3)]);
      }
      short8 bfr[4];
      #pragma unroll
      for (int j = 0; j < 4; ++j) {
        const int row = wn + (j << 4) + (lane & 15);
        bfr[j] = *(const short8*)(&bs[p][(row << 6) + ((c ^ (row & 7)) << 3)]);
      }
      #pragma unroll
      for (int i = 0; i < 4; ++i)
        #pragma unroll
        for (int j = 0; j < 4; ++j)
          acc[i][j] = __builtin_amdgcn_mfma_f32_16x16x32_bf16(af[i], bfr[j], acc[i][j], 0, 0, 0);
    }
    p ^= 1;
  }

  // epilogue: C/D map col=lane&15, row=(lane>>4)*4+r (m89-verified)
  const int q4 = (lane >> 4) << 2;
  if (MODE == 0) {
    #pragma unroll
    for (int i = 0; i < 4; ++i) {
      #pragma unroll
      for (int j = 0; j < 4; ++j) {
        const int nloc = wn + (j << 4) + (lane & 15);
        const float bb = bias[e * HID + hb + nb + nloc];
        #pragma unroll
        for (int r = 0; r < 4; ++r) {
          const int m = m0 + wm + (i << 4) + q4 + r;
          if (m < n_e) {
            float v = acc[i][j][r] + bb;
            v = v / (1.0f + __expf(-v));                 // silu
            hout[(size_t)(offs[e] + m) * Hs + nb + nloc] = f2bf(v);
          }
        }
      }
    }
  } else {
    #pragma unroll
    for (int i = 0; i < 4; ++i) {
      #pragma unroll
      for (int r = 0; r < 4; ++r) {
        const int m = m0 + wm + (i << 4) + q4 + r;
        if (m < n_e) {
          const int   tok = lists_tok[e * NTOK + m];
          const float pp  = lists_p[e * NTOK + m];
          #pragma unroll
          for (int j = 0; j < 4; ++j) {
            const int d = nb + wn + (j << 4) + (lane & 15);
            float v = acc[i][j][r];
            if (hb == 0) v += bias[e * DIM + d];         // add b2 once (first H-slice)
            atomicAdd(out + (size_t)tok * DIM + d, pp * v);
          }
        }
      }
    }
  }
}

extern "C" void kernel_launch(void* const* d_in, const int* in_sizes, int n_in,
                              void* d_out, int out_size, void* d_ws, size_t ws_size,
                              hipStream_t stream)
{
  const float* x      = (const float*)d_in[0];
  const float* gate_w = (const float*)d_in[1];
  const float* gate_b = (const float*)d_in[2];
  const float* w1     = (const float*)d_in[3];
  const float* b1     = (const float*)d_in[4];
  const float* w2     = (const float*)d_in[5];
  const float* b2     = (const float*)d_in[6];
  const float* noise  = (const float*)d_in[7];
  float* out = (float*)d_out;

  char* ws = (char*)d_ws;
  // ws layout (bytes):
  const size_t CNT_OFF = 0;          // int counts[8]
  const size_t OFF_OFF = 64;         // int offs[9]
  const size_t NBK_OFF = 128;        // int nblk[1]
  const size_t TBE_OFF = 192;        // int tbl_e[144]
  const size_t TBM_OFF = 1024;       // int tbl_m[144]
  const size_t LT_OFF  = 2048;       // int  lists_tok[8][8192]   (256 KB)
  const size_t LP_OFF  = LT_OFF + 262144;
  const size_t PA_OFF  = LP_OFF + 262144;
  const size_t XB_OFF  = 1048576;    // bf16 xb[8192][1024]       (16 MB)
  const size_t W_OFF   = 17825792;   // bf16 weight-slice buffer  (32 MB / nsl), then h

  // pick H-slicing: need = W_OFF + 32MB/nsl (wt) + 64MB/nsl (h)
  int nsl = 0;
  for (int cand = 1; cand <= 16; cand <<= 1) {
    const size_t need = W_OFF + (size_t)(33554432 + 67108864) / (size_t)cand;
    if (ws_size >= need) { nsl = cand; break; }
  }
  if (!nsl) return;
  const int Hs = HID / nsl;

  int* counts          = (int*)(ws + CNT_OFF);
  int* offs            = (int*)(ws + OFF_OFF);
  int* nblk            = (int*)(ws + NBK_OFF);
  int* tbl_e           = (int*)(ws + TBE_OFF);
  int* tbl_m           = (int*)(ws + TBM_OFF);
  int* lists_tok       = (int*)(ws + LT_OFF);
  float* lists_p       = (float*)(ws + LP_OFF);
  float* probs_all     = (float*)(ws + PA_OFF);
  unsigned short* xb   = (unsigned short*)(ws + XB_OFF);
  unsigned short* wt   = (unsigned short*)(ws + W_OFF);
  unsigned short* hbuf = (unsigned short*)(ws + W_OFF + (size_t)33554432 / nsl);

  hipMemsetAsync(d_out, 0, (size_t)OUT_MAIN * sizeof(float), stream);
  hipMemsetAsync(ws + CNT_OFF, 0, 64, stream);

  k_gating<<<NTOK / 4, 256, 0, stream>>>(x, gate_w, gate_b, noise, out, counts,
                                         lists_tok, lists_p, probs_all, xb);
  k_offs<<<1, 64, 0, stream>>>(counts, offs, tbl_e, tbl_m, nblk);
  k_aux<<<1, 256, 0, stream>>>(probs_all, out);

  for (int s = 0; s < nsl; ++s) {
    const int hb = s * Hs;
    // w1t slice: in w1[e][d][h], rows d (full 1024), cols h in [hb,hb+Hs) -> wt[e][h'][d]
    dim3 gt1(DIM / 64, Hs / 64, NEXP);
    k_tr<<<gt1, 256, 0, stream>>>(w1, wt, HID, (size_t)DIM * HID, 0, hb,
                                  DIM, (size_t)Hs * DIM);
    dim3 g1(MAXBLK, Hs / 128, 1);
    k_gemm<0><<<g1, 256, 0, stream>>>(xb, wt, b1, counts, offs, tbl_e, tbl_m, nblk,
                                      lists_tok, lists_p, hbuf, out, hb, Hs);
    // w2t slice: in w2[e][h][d], rows h in [hb,hb+Hs), cols d (full 1024) -> wt[e][d][h']
    dim3 gt2(Hs / 64, DIM / 64, NEXP);
    k_tr<<<gt2, 256, 0, stream>>>(w2, wt, DIM, (size_t)DIM * HID, hb, 0,
                                  Hs, (size_t)DIM * Hs);
    dim3 g2(MAXBLK, DIM / 128, 1);
    k_gemm<1><<<g2, 256, 0, stream>>>(hbuf, wt, b2, counts, offs, tbl_e, tbl_m, nblk,
                                      lists_tok, lists_p, hbuf, out, hb, Hs);
  }
}

// Round 4
// 548.069 us; speedup vs baseline: 1.8005x; 1.4213x over previous
//
#include <hip/hip_runtime.h>
#include <stdint.h>

// SparseMoE: B=4,S=2048,D=1024,E=8,H=2048, top-k=2.
// Outputs (concat, float32): final_output[8192*1024], top_k_indices[8192*2] (as floats), aux_loss[1].

#define NTOK   8192
#define DIM    1024
#define NEXP   8
#define HID    2048
#define OUT_MAIN (NTOK * DIM)          // 8388608
#define IDX_OFF  OUT_MAIN
#define AUX_OFF  (OUT_MAIN + NTOK * 2) // 8404992
#define MAXBLK 72                      // >= 64 + 7 worst-case 256-row m-blocks over 8 experts

typedef __attribute__((ext_vector_type(8))) short short8;
typedef __attribute__((ext_vector_type(4))) float floatx4;

__device__ __forceinline__ unsigned short f2bf(float f) {
  unsigned int b = __float_as_uint(f);
  b += 0x7FFFu + ((b >> 16) & 1u);      // RNE; inputs finite
  return (unsigned short)(b >> 16);
}

// ---------------- gating: logits (fp64 acc), top-2, masked softmax, scatter, xb=bf16(x) ---
// 1024 threads = 16 waves = 16 tokens/block; LDS-aggregated scatter (4x fewer global atomics).
__global__ __launch_bounds__(1024) void k_gating(
    const float* __restrict__ x, const float* __restrict__ gate_w,
    const float* __restrict__ gate_b, const float* __restrict__ noise,
    float* __restrict__ out, int* __restrict__ counts,
    int* __restrict__ lists_tok, float* __restrict__ lists_p,
    float* __restrict__ probs_all, unsigned short* __restrict__ xb)
{
  const int lane = threadIdx.x & 63;
  const int wv   = threadIdx.x >> 6;              // 0..15
  const int t    = blockIdx.x * 16 + wv;          // one token per wave
  const float* xr = x + (size_t)t * DIM;

  __shared__ int   cnt[NEXP];
  __shared__ int   base[NEXP];
  __shared__ int   s_e[32];
  __shared__ int   s_pos[32];
  __shared__ float s_p[32];
  if (threadIdx.x < NEXP) cnt[threadIdx.x] = 0;

  double acc[NEXP] = {0,0,0,0,0,0,0,0};
  #pragma unroll
  for (int jj = 0; jj < 4; ++jj) {
    const int d0 = lane * 4 + jj * 256;
    const float4 xv = *(const float4*)(xr + d0);
    const float xs[4] = {xv.x, xv.y, xv.z, xv.w};
    unsigned short xbq[4];
    #pragma unroll
    for (int c = 0; c < 4; ++c) {
      const float4 g0 = *(const float4*)(gate_w + (size_t)(d0 + c) * NEXP);
      const float4 g1 = *(const float4*)(gate_w + (size_t)(d0 + c) * NEXP + 4);
      const double xd = (double)xs[c];
      acc[0] += xd * (double)g0.x; acc[1] += xd * (double)g0.y;
      acc[2] += xd * (double)g0.z; acc[3] += xd * (double)g0.w;
      acc[4] += xd * (double)g1.x; acc[5] += xd * (double)g1.y;
      acc[6] += xd * (double)g1.z; acc[7] += xd * (double)g1.w;
      xbq[c] = f2bf(xs[c]);
    }
    ushort4 q; q.x = xbq[0]; q.y = xbq[1]; q.z = xbq[2]; q.w = xbq[3];
    *(ushort4*)(xb + (size_t)t * DIM + d0) = q;
  }
  #pragma unroll
  for (int e = 0; e < NEXP; ++e) {
    #pragma unroll
    for (int off = 32; off; off >>= 1) acc[e] += __shfl_xor(acc[e], off);
  }
  __syncthreads();                                 // cnt[] initialized
  if (lane == 0) {
    double l[NEXP];
    #pragma unroll
    for (int e = 0; e < NEXP; ++e)
      l[e] = acc[e] + (double)gate_b[e] + 0.01 * (double)noise[(size_t)t * NEXP + e];
    // top-2 with jax.lax.top_k tie semantics (stable desc: earliest index wins)
    int i1 = 0; double v1 = l[0];
    #pragma unroll
    for (int e = 1; e < NEXP; ++e) if (l[e] > v1) { v1 = l[e]; i1 = e; }
    int i2 = (i1 == 0) ? 1 : 0; double v2 = l[i2];
    #pragma unroll
    for (int e = 0; e < NEXP; ++e) if (e != i1 && l[e] > v2) { v2 = l[e]; i2 = e; }
    // masked softmax over all 8 (mask = logit >= v2), max is v1
    float pr[NEXP]; float Z = 0.f;
    #pragma unroll
    for (int e = 0; e < NEXP; ++e) {
      const float a = (l[e] >= v2) ? (float)(l[e] - v1) : -1.0e9f;
      pr[e] = __expf(a); Z += pr[e];
    }
    const float rz = 1.0f / Z;
    #pragma unroll
    for (int e = 0; e < NEXP; ++e) {
      pr[e] *= rz;
      probs_all[(size_t)t * NEXP + e] = pr[e];
    }
    out[(size_t)IDX_OFF + t * 2]     = (float)i1;
    out[(size_t)IDX_OFF + t * 2 + 1] = (float)i2;
    const int p1 = atomicAdd(&cnt[i1], 1);
    const int p2 = atomicAdd(&cnt[i2], 1);
    s_e[wv * 2]     = i1; s_pos[wv * 2]     = p1; s_p[wv * 2]     = pr[i1];
    s_e[wv * 2 + 1] = i2; s_pos[wv * 2 + 1] = p2; s_p[wv * 2 + 1] = pr[i2];
  }
  __syncthreads();
  if (threadIdx.x < NEXP) base[threadIdx.x] = atomicAdd(&counts[threadIdx.x], cnt[threadIdx.x]);
  __syncthreads();
  if (lane == 0) {
    #pragma unroll
    for (int k = 0; k < 2; ++k) {
      const int ee  = s_e[wv * 2 + k];
      const int pos = base[ee] + s_pos[wv * 2 + k];
      lists_tok[ee * NTOK + pos] = t;
      lists_p[ee * NTOK + pos]   = s_p[wv * 2 + k];
    }
  }
}

// ---------------- offsets + block table (256-row m-granularity) ----------------
__global__ void k_offs(const int* __restrict__ counts, int* __restrict__ offs,
                       int* __restrict__ tbl_e, int* __restrict__ tbl_m,
                       int* __restrict__ nblk) {
  if (threadIdx.x == 0) {
    int a = 0;
    #pragma unroll
    for (int e = 0; e < NEXP; ++e) { offs[e] = a; a += counts[e]; }
    offs[NEXP] = a;
    int nb = 0;
    for (int e = 0; e < NEXP; ++e) {
      const int nbe = (counts[e] + 255) >> 8;
      for (int m = 0; m < nbe; ++m) { tbl_e[nb] = e; tbl_m[nb] = m << 8; ++nb; }
    }
    nblk[0] = nb;
    for (int b = nb; b < MAXBLK; ++b) { tbl_e[b] = 0; tbl_m[b] = 0; }
  }
}

// ---------------- aux loss ----------------
__global__ __launch_bounds__(256) void k_aux(const float* __restrict__ probs_all,
                                             float* __restrict__ out) {
  float p[NEXP] = {0,0,0,0,0,0,0,0};
  for (int t = threadIdx.x; t < NTOK; t += 256) {
    const float4 a = *(const float4*)(probs_all + (size_t)t * NEXP);
    const float4 b = *(const float4*)(probs_all + (size_t)t * NEXP + 4);
    p[0] += a.x; p[1] += a.y; p[2] += a.z; p[3] += a.w;
    p[4] += b.x; p[5] += b.y; p[6] += b.z; p[7] += b.w;
  }
  #pragma unroll
  for (int e = 0; e < NEXP; ++e) {
    #pragma unroll
    for (int off = 32; off; off >>= 1) p[e] += __shfl_xor(p[e], off);
  }
  __shared__ float red[4][NEXP];
  const int lane = threadIdx.x & 63, wv = threadIdx.x >> 6;
  if (lane == 0) {
    #pragma unroll
    for (int e = 0; e < NEXP; ++e) red[wv][e] = p[e];
  }
  __syncthreads();
  if (threadIdx.x == 0) {
    float usage[NEXP], s = 0.f;
    #pragma unroll
    for (int e = 0; e < NEXP; ++e) {
      usage[e] = red[0][e] + red[1][e] + red[2][e] + red[3][e];
      s += usage[e];
    }
    float imp[NEXP], mean = 0.f, var = 0.f;
    #pragma unroll
    for (int e = 0; e < NEXP; ++e) { imp[e] = usage[e] / s; mean += imp[e]; }
    mean *= 0.125f;
    #pragma unroll
    for (int e = 0; e < NEXP; ++e) { const float d = imp[e] - mean; var += d * d; }
    var *= 0.125f;
    out[AUX_OFF] = sqrtf(var) / (mean + 1e-10f);
  }
}

// ---------------- weight transpose+convert: in[e][r][c] fp32 -> out[e][c-c0][r-r0] bf16 ---
__global__ __launch_bounds__(256) void k_tr(
    const float* __restrict__ in, unsigned short* __restrict__ out,
    int in_ld, size_t in_estride, int r0, int c0,
    int out_ld, size_t out_estride)
{
  const int e  = blockIdx.z;
  const int tr = blockIdx.x << 6;
  const int tc = blockIdx.y << 6;
  const int tid = threadIdx.x;
  __shared__ float t[64][65];
  const float* src = in + (size_t)e * in_estride + (size_t)(r0 + tr) * in_ld + (c0 + tc);
  #pragma unroll
  for (int p = 0; p < 4; ++p) {
    const int r  = (p << 4) + (tid >> 4);
    const int c4 = (tid & 15) << 2;
    const float4 v = *(const float4*)(src + (size_t)r * in_ld + c4);
    t[r][c4] = v.x; t[r][c4 + 1] = v.y; t[r][c4 + 2] = v.z; t[r][c4 + 3] = v.w;
  }
  __syncthreads();
  unsigned short* dst = out + (size_t)e * out_estride + (size_t)tc * out_ld + tr;
  #pragma unroll
  for (int p = 0; p < 4; ++p) {
    const int c  = (p << 4) + (tid >> 4);
    const int r4 = (tid & 15) << 2;
    ushort4 q;
    q.x = f2bf(t[r4][c]);     q.y = f2bf(t[r4 + 1][c]);
    q.z = f2bf(t[r4 + 2][c]); q.w = f2bf(t[r4 + 3][c]);
    *(ushort4*)(dst + (size_t)c * out_ld + r4) = q;
  }
}

// ---------------- grouped MFMA GEMM: 256x256 tile, 16 waves, BK=32, dbuf 64 KB LDS -----
// MODE 0: h[slot, nb+n] = silu( xb[tok] @ w1t[e][nb+n][:] + b1 )   (K = 1024, N = Hs)
// MODE 1 (split-K=2): out[tok, nb+n] += p * ( h[slot] @ w2t[e][nb+n][:] + b2 )
// LDS [row][32] with 16B-chunk XOR swizzle: chunk c of row r at slot c^(r&3)
// (global source permuted per lane; global_load_lds dest is wave-base + lane*16).
template <int MODE>
__global__ __launch_bounds__(1024) void k_gemm(
    const unsigned short* __restrict__ Abase,
    const unsigned short* __restrict__ Bt,
    const float* __restrict__ bias,
    const int* __restrict__ counts, const int* __restrict__ offs,
    const int* __restrict__ tbl_e, const int* __restrict__ tbl_m,
    const int* __restrict__ nblk,
    const int* __restrict__ lists_tok, const float* __restrict__ lists_p,
    unsigned short* __restrict__ hout, float* __restrict__ out,
    const int hb, const int Hs)
{
  if ((int)blockIdx.x >= nblk[0]) return;
  const int e   = tbl_e[blockIdx.x];
  const int m0  = tbl_m[blockIdx.x];
  const int n_e = counts[e];

  int nb, k0g, Kloc;
  if (MODE == 0) { nb = blockIdx.y << 8; k0g = 0; Kloc = DIM; }
  else { nb = (blockIdx.y >> 1) << 8; const int half = Hs >> 1;
         k0g = (blockIdx.y & 1) * half; Kloc = half; }

  const int tid  = threadIdx.x;
  const int lane = tid & 63;
  const int wv   = tid >> 6;                 // 0..15
  const int wm   = (wv & 3) << 6;
  const int wn   = (wv >> 2) << 6;

  __shared__ __align__(16) unsigned short as[2][256 * 32];  // 2 x 16 KB
  __shared__ __align__(16) unsigned short bs[2][256 * 32];  // 2 x 16 KB

  const int K = (MODE == 0) ? DIM : Hs;      // row stride of both A and B
  const unsigned short* Bexp = Bt + (size_t)e * ((size_t)DIM * Hs) + (size_t)nb * K + k0g;

  // staging: 1 A + 1 B call per wave; lane covers row rbase+(lane>>2), chunk lane&3,
  // reading global chunk (lane&3)^((lane>>2)&3)  ->  LDS[r][c] = global[r][c^(r&3)]
  const int swk   = (((lane & 3) ^ ((lane >> 2) & 3)) << 3);
  const int rbase = wv << 4;
  const int r     = rbase + (lane >> 2);
  const int rcA   = (m0 + r < n_e) ? (m0 + r) : (n_e - 1);
  size_t arow;
  if (MODE == 0) arow = (size_t)lists_tok[e * NTOK + rcA] * DIM;
  else           arow = (size_t)(offs[e] + rcA) * Hs;
  const unsigned short* gpa = Abase + arow + k0g + swk;
  const unsigned short* gpb = Bexp + (size_t)r * K + swk;
  unsigned short* lpa0 = &as[0][rbase << 5];
  unsigned short* lpb0 = &bs[0][rbase << 5];
  unsigned short* lpa1 = &as[1][rbase << 5];
  unsigned short* lpb1 = &bs[1][rbase << 5];

  floatx4 acc[4][4];
  #pragma unroll
  for (int i = 0; i < 4; ++i)
    #pragma unroll
    for (int j = 0; j < 4; ++j) acc[i][j] = (floatx4){0.f, 0.f, 0.f, 0.f};

  auto issue = [&](int buf, int kko) {
    __builtin_amdgcn_global_load_lds(
        (const __attribute__((address_space(1))) void*)(gpa + kko),
        (__attribute__((address_space(3))) void*)(void*)(buf ? lpa1 : lpa0), 16, 0, 0);
    __builtin_amdgcn_global_load_lds(
        (const __attribute__((address_space(1))) void*)(gpb + kko),
        (__attribute__((address_space(3))) void*)(void*)(buf ? lpb1 : lpb0), 16, 0, 0);
  };

  issue(0, 0);
  int p = 0;
  for (int kk = 0; kk < Kloc; kk += 32) {
    __syncthreads();                             // drains tile-kk loads
    if (kk + 32 < Kloc) issue(p ^ 1, kk + 32);   // next tile in flight during compute
    const int c = lane >> 4;                     // 16B-chunk 0..3
    short8 af[4];
    #pragma unroll
    for (int i = 0; i < 4; ++i) {
      const int row = wm + (i << 4) + (lane & 15);
      af[i] = *(const short8*)(&as[p][(row << 5) + ((c ^ (row & 3)) << 3)]);
    }
    short8 bfr[4];
    #pragma unroll
    for (int j = 0; j < 4; ++j) {
      const int row = wn + (j << 4) + (lane & 15);
      bfr[j] = *(const short8*)(&bs[p][(row << 5) + ((c ^ (row & 3)) << 3)]);
    }
    #pragma unroll
    for (int i = 0; i < 4; ++i)
      #pragma unroll
      for (int j = 0; j < 4; ++j)
        acc[i][j] = __builtin_amdgcn_mfma_f32_16x16x32_bf16(af[i], bfr[j], acc[i][j], 0, 0, 0);
    p ^= 1;
  }

  // epilogue: C/D map col=lane&15, row=(lane>>4)*4+r (m89-verified)
  const int q4 = (lane >> 4) << 2;
  if (MODE == 0) {
    #pragma unroll
    for (int i = 0; i < 4; ++i) {
      #pragma unroll
      for (int j = 0; j < 4; ++j) {
        const int nloc = wn + (j << 4) + (lane & 15);
        const float bb = bias[e * HID + hb + nb + nloc];
        #pragma unroll
        for (int rr = 0; rr < 4; ++rr) {
          const int m = m0 + wm + (i << 4) + q4 + rr;
          if (m < n_e) {
            float v = acc[i][j][rr] + bb;
            v = v / (1.0f + __expf(-v));                 // silu
            hout[(size_t)(offs[e] + m) * Hs + nb + nloc] = f2bf(v);
          }
        }
      }
    }
  } else {
    #pragma unroll
    for (int i = 0; i < 4; ++i) {
      #pragma unroll
      for (int rr = 0; rr < 4; ++rr) {
        const int m = m0 + wm + (i << 4) + q4 + rr;
        if (m < n_e) {
          const int   tok = lists_tok[e * NTOK + m];
          const float pp  = lists_p[e * NTOK + m];
          #pragma unroll
          for (int j = 0; j < 4; ++j) {
            const int d = nb + wn + (j << 4) + (lane & 15);
            float v = acc[i][j][rr];
            if (hb == 0 && k0g == 0) v += bias[e * DIM + d];   // add b2 exactly once
            atomicAdd(out + (size_t)tok * DIM + d, pp * v);
          }
        }
      }
    }
  }
}

extern "C" void kernel_launch(void* const* d_in, const int* in_sizes, int n_in,
                              void* d_out, int out_size, void* d_ws, size_t ws_size,
                              hipStream_t stream)
{
  const float* x      = (const float*)d_in[0];
  const float* gate_w = (const float*)d_in[1];
  const float* gate_b = (const float*)d_in[2];
  const float* w1     = (const float*)d_in[3];
  const float* b1     = (const float*)d_in[4];
  const float* w2     = (const float*)d_in[5];
  const float* b2     = (const float*)d_in[6];
  const float* noise  = (const float*)d_in[7];
  float* out = (float*)d_out;

  char* ws = (char*)d_ws;
  const size_t CNT_OFF = 0;          // int counts[8]
  const size_t OFF_OFF = 64;         // int offs[9]
  const size_t NBK_OFF = 128;        // int nblk[1]
  const size_t TBE_OFF = 192;        // int tbl_e[72]
  const size_t TBM_OFF = 1024;       // int tbl_m[72]
  const size_t LT_OFF  = 2048;       // int  lists_tok[8][8192]   (256 KB)
  const size_t LP_OFF  = LT_OFF + 262144;
  const size_t PA_OFF  = LP_OFF + 262144;
  const size_t XB_OFF  = 1048576;    // bf16 xb[8192][1024]       (16 MB)
  const size_t W_OFF   = 17825792;   // bf16 weight-slice buffer  (32 MB / nsl), then h

  // pick H-slicing: need = W_OFF + 32MB/nsl (wt) + 64MB/nsl (h); Hs >= 256 required
  int nsl = 0;
  for (int cand = 1; cand <= 8; cand <<= 1) {
    const size_t need = W_OFF + (size_t)(33554432 + 67108864) / (size_t)cand;
    if (ws_size >= need) { nsl = cand; break; }
  }
  if (!nsl) return;
  const int Hs = HID / nsl;

  int* counts          = (int*)(ws + CNT_OFF);
  int* offs            = (int*)(ws + OFF_OFF);
  int* nblk            = (int*)(ws + NBK_OFF);
  int* tbl_e           = (int*)(ws + TBE_OFF);
  int* tbl_m           = (int*)(ws + TBM_OFF);
  int* lists_tok       = (int*)(ws + LT_OFF);
  float* lists_p       = (float*)(ws + LP_OFF);
  float* probs_all     = (float*)(ws + PA_OFF);
  unsigned short* xb   = (unsigned short*)(ws + XB_OFF);
  unsigned short* wt   = (unsigned short*)(ws + W_OFF);
  unsigned short* hbuf = (unsigned short*)(ws + W_OFF + (size_t)33554432 / nsl);

  hipMemsetAsync(d_out, 0, (size_t)OUT_MAIN * sizeof(float), stream);
  hipMemsetAsync(ws + CNT_OFF, 0, 64, stream);

  k_gating<<<NTOK / 16, 1024, 0, stream>>>(x, gate_w, gate_b, noise, out, counts,
                                           lists_tok, lists_p, probs_all, xb);
  k_offs<<<1, 64, 0, stream>>>(counts, offs, tbl_e, tbl_m, nblk);
  k_aux<<<1, 256, 0, stream>>>(probs_all, out);

  for (int s = 0; s < nsl; ++s) {
    const int hb = s * Hs;
    // w1t slice: w1[e][d][h], rows d (1024), cols h in [hb,hb+Hs) -> wt[e][h'][d]
    dim3 gt1(DIM / 64, Hs / 64, NEXP);
    k_tr<<<gt1, 256, 0, stream>>>(w1, wt, HID, (size_t)DIM * HID, 0, hb,
                                  DIM, (size_t)Hs * DIM);
    dim3 g1(MAXBLK, Hs / 256, 1);
    k_gemm<0><<<g1, 1024, 0, stream>>>(xb, wt, b1, counts, offs, tbl_e, tbl_m, nblk,
                                       lists_tok, lists_p, hbuf, out, hb, Hs);
    // w2t slice: w2[e][h][d], rows h in [hb,hb+Hs), cols d (1024) -> wt[e][d][h']
    dim3 gt2(Hs / 64, DIM / 64, NEXP);
    k_tr<<<gt2, 256, 0, stream>>>(w2, wt, DIM, (size_t)DIM * HID, hb, 0,
                                  Hs, (size_t)DIM * Hs);
    dim3 g2(MAXBLK, (DIM / 256) * 2, 1);   // x2 = split-K
    k_gemm<1><<<g2, 1024, 0, stream>>>(hbuf, wt, b2, counts, offs, tbl_e, tbl_m, nblk,
                                       lists_tok, lists_p, hbuf, out, hb, Hs);
  }
}